// Round 9
// baseline (47.810 us; speedup 1.0000x reference)
//
#include <hip/hip_runtime.h>
#include <math.h>

namespace {

constexpr int kD = 1024;
constexpr int kL = 1024;
constexpr int kN = 16;
constexpr int kE = 8;    // l-steps per thread
constexpr int kJ = 4;    // n-states per thread
constexpr int kT = 512;  // threads per block; block = one (b,d)

__global__ __launch_bounds__(kT)
void selscan(const float* __restrict__ u,
             const float* __restrict__ delta,
             const float* __restrict__ A,
             const float* __restrict__ Bm,
             const float* __restrict__ Cm,
             const float* __restrict__ Dv,
             const float* __restrict__ z,
             float* __restrict__ out)
{
    // chunk summaries (a,x) per [chunk][n]; +1 float2 pad per row.
    // After the scanner pass, .x of each slot holds the exclusive carry.
    __shared__ float2 sax[128][kN + 1];   // 17408 B

    const int bd   = blockIdx.x;
    const int b    = bd >> 10;          // kD = 1024
    const int d    = bd & (kD - 1);
    const int t    = threadIdx.x;
    const int lane = t & 63;
    const int wave = t >> 6;
    const int ng   = t & 3;             // n-group: states 4*ng .. 4*ng+3
    const int n0   = ng << 2;
    const int chunk = t >> 2;           // 0..127
    const int l0   = chunk << 3;        // 8 elements per chunk
    const size_t base = (size_t)bd * kL;

    const float LOG2E = 1.4426950408889634f;
    const float LN2   = 0.6931471805599453f;

    // ---- dt = softplus(delta), dtu = dt*u (4x redundant across ng) ----
    float dt[kE], dtu[kE];
    float4 u0, u1;
    {
        float4 d0 = *(const float4*)(delta + base + l0);
        float4 d1 = *(const float4*)(delta + base + l0 + 4);
        u0 = *(const float4*)(u + base + l0);
        u1 = *(const float4*)(u + base + l0 + 4);
        float dd[kE] = {d0.x,d0.y,d0.z,d0.w,d1.x,d1.y,d1.z,d1.w};
        float uu[kE] = {u0.x,u0.y,u0.z,u0.w,u1.x,u1.y,u1.z,u1.w};
        #pragma unroll
        for (int s = 0; s < kE; ++s) {
            float x = dd[s];
            float e = __builtin_amdgcn_exp2f(-fabsf(x) * LOG2E);
            float sp = fmaxf(x, 0.f) + __builtin_amdgcn_logf(1.f + e) * LN2;
            dt[s]  = sp;
            dtu[s] = sp * uu[s];
        }
    }

    // ---- A row, pre-scaled by log2(e) for exp2 ----
    float cj[kJ];
    {
        float4 a4 = *(const float4*)(A + d * kN + n0);
        cj[0]=a4.x*LOG2E; cj[1]=a4.y*LOG2E; cj[2]=a4.z*LOG2E; cj[3]=a4.w*LOG2E;
    }

    // ---- Phase 1: local scan; accumulate y_local and Q = P*C ----
    float Q[kJ][kE];
    float y[kE] = {0.f,0.f,0.f,0.f,0.f,0.f,0.f,0.f};
    const int rowbase = (b << 4) + n0;
    #pragma unroll
    for (int j = 0; j < kJ; ++j) {
        const float* Bp = Bm + (size_t)(rowbase + j) * kL + l0;
        const float* Cp = Cm + (size_t)(rowbase + j) * kL + l0;
        float4 b0 = *(const float4*)Bp;
        float4 b1 = *(const float4*)(Bp + 4);
        float4 c0 = *(const float4*)Cp;
        float4 c1 = *(const float4*)(Cp + 4);
        float Bv[kE] = {b0.x,b0.y,b0.z,b0.w,b1.x,b1.y,b1.z,b1.w};
        float Cv[kE] = {c0.x,c0.y,c0.z,c0.w,c1.x,c1.y,c1.z,c1.w};
        float x = 0.f, p = 1.f;
        #pragma unroll
        for (int s = 0; s < kE; ++s) {
            float e = __builtin_amdgcn_exp2f(dt[s] * cj[j]);
            x = fmaf(e, x, dtu[s] * Bv[s]);
            p *= e;
            Q[j][s] = p * Cv[s];
            y[s] = fmaf(x, Cv[s], y[s]);
        }
        sax[chunk][n0 + j] = make_float2(p, x);
    }
    __syncthreads();

    // ---- Scanner: wave 0 computes exclusive carries for all 128 chunks ----
    if (wave == 0) {
        const int sn = lane & 15;       // state n
        const int q  = lane >> 4;       // chunk group (32 chunks each)
        const int cb = q << 5;
        float p = 1.f, c = 0.f;
        #pragma unroll 8
        for (int i = 0; i < 32; ++i) {
            float2 ax = sax[cb + i][sn];
            c = fmaf(ax.x, c, ax.y);
            p *= ax.x;
        }
        float Ag = p, Xg = c;
        {
            float ain = __shfl_up(Ag, 16, 64);
            float xin = __shfl_up(Xg, 16, 64);
            bool act = (lane >= 16);
            Xg = fmaf(Ag, act ? xin : 0.f, Xg);
            Ag *= act ? ain : 1.f;
            ain = __shfl_up(Ag, 32, 64);
            xin = __shfl_up(Xg, 32, 64);
            act = (lane >= 32);
            Xg = fmaf(Ag, act ? xin : 0.f, Xg);
            Ag *= act ? ain : 1.f;
        }
        float gx = __shfl_up(Xg, 16, 64);
        float cc = (lane >= 16) ? gx : 0.f;
        #pragma unroll 8
        for (int i = 0; i < 32; ++i) {
            float2 ax = sax[cb + i][sn];
            sax[cb + i][sn].x = cc;
            cc = fmaf(ax.x, cc, ax.y);
        }
    }
    __syncthreads();

    // ---- Phase 2: y += carry_j * Q_j (carries straight from LDS) ----
    #pragma unroll
    for (int j = 0; j < kJ; ++j) {
        float carry = sax[chunk][n0 + j].x;
        #pragma unroll
        for (int s = 0; s < kE; ++s)
            y[s] = fmaf(carry, Q[j][s], y[s]);
    }

    // ---- Reduce over the 4 n-groups (lane bits 0-1) ----
    #pragma unroll
    for (int s = 0; s < kE; ++s) {
        y[s] += __shfl_xor(y[s], 1, 64);
        y[s] += __shfl_xor(y[s], 2, 64);
    }

    // ---- Epilogue: thread writes l = 2t, 2t+1 (constant-index selects) ----
    const float D_d = Dv[d];
    bool g2 = (ng & 2) != 0, g1 = (ng & 1) != 0;
    float ya  = g2 ? (g1 ? y[6] : y[4]) : (g1 ? y[2] : y[0]);
    float yb  = g2 ? (g1 ? y[7] : y[5]) : (g1 ? y[3] : y[1]);
    float ue0 = g2 ? (g1 ? u1.z : u1.x) : (g1 ? u0.z : u0.x);
    float ue1 = g2 ? (g1 ? u1.w : u1.y) : (g1 ? u0.w : u0.y);

    const int eo = 2 * t;   // == l0 + 2*ng, coalesced
    float2 zv = *(const float2*)(z + base + eo);
    float s0 = __builtin_amdgcn_rcpf(1.f + __builtin_amdgcn_exp2f(-zv.x * LOG2E));
    float s1 = __builtin_amdgcn_rcpf(1.f + __builtin_amdgcn_exp2f(-zv.y * LOG2E));
    float2 o;
    o.x = (ya + ue0 * D_d) * zv.x * s0;
    o.y = (yb + ue1 * D_d) * zv.y * s1;
    *(float2*)(out + base + eo) = o;
}

}  // namespace

extern "C" void kernel_launch(void* const* d_in, const int* in_sizes, int n_in,
                              void* d_out, int out_size, void* d_ws, size_t ws_size,
                              hipStream_t stream) {
    const float* u     = (const float*)d_in[0];
    const float* delta = (const float*)d_in[1];
    const float* A     = (const float*)d_in[2];
    const float* Bm    = (const float*)d_in[3];
    const float* Cm    = (const float*)d_in[4];
    const float* Dv    = (const float*)d_in[5];
    const float* z     = (const float*)d_in[6];
    float* out = (float*)d_out;

    dim3 grid(2 * kD);
    dim3 block(kT);
    hipLaunchKernelGGL(selscan, grid, block, 0, stream,
                       u, delta, A, Bm, Cm, Dv, z, out);
}

// Round 10
// 31.116 us; speedup vs baseline: 1.5365x; 1.5365x over previous
//
#include <hip/hip_runtime.h>
#include <math.h>

namespace {

constexpr int kD = 1024;
constexpr int kL = 1024;
constexpr int kN = 16;
constexpr int kE = 8;    // l-steps per thread
constexpr int kJ = 8;    // n-states per thread
constexpr int kT = 256;  // threads per block; block = one (b,d)

__global__ __launch_bounds__(kT)
void selscan(const float* __restrict__ u,
             const float* __restrict__ delta,
             const float* __restrict__ A,
             const float* __restrict__ Bm,
             const float* __restrict__ Cm,
             const float* __restrict__ Dv,
             const float* __restrict__ z,
             float* __restrict__ out)
{
    // chunk summaries (a,x) per [chunk][n]; +1 float2 pad per row.
    // After the scanner pass, .x of each slot holds the exclusive carry.
    __shared__ float2 sax[128][kN + 1];   // 17408 B

    const int bd   = blockIdx.x;
    const int b    = bd >> 10;          // kD = 1024
    const int d    = bd & (kD - 1);
    const int t    = threadIdx.x;
    const int lane = t & 63;
    const int wave = t >> 6;
    const int nh   = t & 1;             // which half of n
    const int n0   = nh << 3;
    const int chunk = t >> 1;           // 0..127
    const int l0   = chunk << 3;        // 8 elements per chunk
    const size_t base = (size_t)bd * kL;
    const int eoff = l0 + nh * 4;       // epilogue offset (== 4*t)

    const float LOG2E = 1.4426950408889634f;
    const float LN2   = 0.6931471805599453f;

    const float D_d = Dv[d];

    // ---- dt = softplus(delta), dtu = dt*u; fold u*D for epilogue ----
    float dt[kE], dtu[kE];
    float ue0, ue1, ue2, ue3;
    {
        float4 d0 = *(const float4*)(delta + base + l0);
        float4 d1 = *(const float4*)(delta + base + l0 + 4);
        float4 u0 = *(const float4*)(u + base + l0);
        float4 u1 = *(const float4*)(u + base + l0 + 4);
        float dd[kE] = {d0.x,d0.y,d0.z,d0.w,d1.x,d1.y,d1.z,d1.w};
        float uu[kE] = {u0.x,u0.y,u0.z,u0.w,u1.x,u1.y,u1.z,u1.w};
        #pragma unroll
        for (int s = 0; s < kE; ++s) {
            float x = dd[s];
            float e = __builtin_amdgcn_exp2f(-fabsf(x) * LOG2E);
            float sp = fmaxf(x, 0.f) + __builtin_amdgcn_logf(1.f + e) * LN2;
            dt[s]  = sp;
            dtu[s] = sp * uu[s];
        }
        // epilogue u*D (elements eoff..eoff+3); u0/u1 die here
        ue0 = (nh ? u1.x : u0.x) * D_d;
        ue1 = (nh ? u1.y : u0.y) * D_d;
        ue2 = (nh ? u1.z : u0.z) * D_d;
        ue3 = (nh ? u1.w : u0.w) * D_d;
    }

    // ---- dt prefix sums: T[s] = sum_{k<=s} dt[k] ----
    float T[kE];
    T[0] = dt[0];
    #pragma unroll
    for (int s = 1; s < kE; ++s) T[s] = T[s - 1] + dt[s];

    // ---- A row, pre-scaled by log2(e) for exp2 ----
    float cj[kJ];
    {
        float4 a0 = *(const float4*)(A + d * kN + n0);
        float4 a1 = *(const float4*)(A + d * kN + n0 + 4);
        cj[0]=a0.x*LOG2E; cj[1]=a0.y*LOG2E; cj[2]=a0.z*LOG2E; cj[3]=a0.w*LOG2E;
        cj[4]=a1.x*LOG2E; cj[5]=a1.y*LOG2E; cj[6]=a1.z*LOG2E; cj[7]=a1.w*LOG2E;
    }

    // ---- Phase 1: local scan; accumulate y_local; summaries to LDS ----
    float y[kE] = {0.f,0.f,0.f,0.f,0.f,0.f,0.f,0.f};
    const int rowbase = (b << 4) + n0;
    #pragma unroll
    for (int j = 0; j < kJ; ++j) {
        const float* Bp = Bm + (size_t)(rowbase + j) * kL + l0;
        const float* Cp = Cm + (size_t)(rowbase + j) * kL + l0;
        float4 b0 = *(const float4*)Bp;
        float4 b1 = *(const float4*)(Bp + 4);
        float4 c0 = *(const float4*)Cp;
        float4 c1 = *(const float4*)(Cp + 4);
        float Bv[kE] = {b0.x,b0.y,b0.z,b0.w,b1.x,b1.y,b1.z,b1.w};
        float Cv[kE] = {c0.x,c0.y,c0.z,c0.w,c1.x,c1.y,c1.z,c1.w};
        float x = 0.f;
        #pragma unroll
        for (int s = 0; s < kE; ++s) {
            float e = __builtin_amdgcn_exp2f(dt[s] * cj[j]);
            x = fmaf(e, x, dtu[s] * Bv[s]);
            y[s] = fmaf(x, Cv[s], y[s]);
        }
        float a = __builtin_amdgcn_exp2f(T[kE - 1] * cj[j]);  // full-chunk decay
        sax[chunk][n0 + j] = make_float2(a, x);
    }
    __syncthreads();

    // ---- Scanner: wave 0 computes exclusive carries for all 128 chunks ----
    if (wave == 0) {
        const int sn = lane & 15;       // state n
        const int q  = lane >> 4;       // chunk group (32 chunks each)
        const int cb = q << 5;
        float p = 1.f, c = 0.f;
        #pragma unroll 8
        for (int i = 0; i < 32; ++i) {
            float2 ax = sax[cb + i][sn];
            c = fmaf(ax.x, c, ax.y);
            p *= ax.x;
        }
        float Ag = p, Xg = c;
        {
            float ain = __shfl_up(Ag, 16, 64);
            float xin = __shfl_up(Xg, 16, 64);
            bool act = (lane >= 16);
            Xg = fmaf(Ag, act ? xin : 0.f, Xg);
            Ag *= act ? ain : 1.f;
            ain = __shfl_up(Ag, 32, 64);
            xin = __shfl_up(Xg, 32, 64);
            act = (lane >= 32);
            Xg = fmaf(Ag, act ? xin : 0.f, Xg);
            Ag *= act ? ain : 1.f;
        }
        float gx = __shfl_up(Xg, 16, 64);
        float cc = (lane >= 16) ? gx : 0.f;
        #pragma unroll 8
        for (int i = 0; i < 32; ++i) {
            float2 ax = sax[cb + i][sn];
            sax[cb + i][sn].x = cc;
            cc = fmaf(ax.x, cc, ax.y);
        }
    }
    __syncthreads();

    // ---- Phase 2: y += carry_j * exp2(T[s]*cj[j]) * C[j][s] (C reloaded, L2-hot) ----
    #pragma unroll
    for (int j = 0; j < kJ; ++j) {
        const float* Cp = Cm + (size_t)(rowbase + j) * kL + l0;
        float4 c0 = *(const float4*)Cp;
        float4 c1 = *(const float4*)(Cp + 4);
        float Cv[kE] = {c0.x,c0.y,c0.z,c0.w,c1.x,c1.y,c1.z,c1.w};
        float carry = sax[chunk][n0 + j].x;
        #pragma unroll
        for (int s = 0; s < kE; ++s) {
            float p = __builtin_amdgcn_exp2f(T[s] * cj[j]);
            y[s] = fmaf(carry * p, Cv[s], y[s]);
        }
    }

    // ---- Combine the two n-halves (lane pairs) ----
    #pragma unroll
    for (int s = 0; s < kE; ++s) y[s] += __shfl_xor(y[s], 1, 64);

    // ---- Epilogue: z loaded late; constant-index selects ----
    float y0 = nh ? y[4] : y[0];
    float y1 = nh ? y[5] : y[1];
    float y2 = nh ? y[6] : y[2];
    float y3 = nh ? y[7] : y[3];

    float4 zv = *(const float4*)(z + base + eoff);
    float s0 = __builtin_amdgcn_rcpf(1.f + __builtin_amdgcn_exp2f(-zv.x * LOG2E));
    float s1 = __builtin_amdgcn_rcpf(1.f + __builtin_amdgcn_exp2f(-zv.y * LOG2E));
    float s2 = __builtin_amdgcn_rcpf(1.f + __builtin_amdgcn_exp2f(-zv.z * LOG2E));
    float s3 = __builtin_amdgcn_rcpf(1.f + __builtin_amdgcn_exp2f(-zv.w * LOG2E));
    float4 o;
    o.x = (y0 + ue0) * zv.x * s0;
    o.y = (y1 + ue1) * zv.y * s1;
    o.z = (y2 + ue2) * zv.z * s2;
    o.w = (y3 + ue3) * zv.w * s3;
    *(float4*)(out + base + eoff) = o;
}

}  // namespace

extern "C" void kernel_launch(void* const* d_in, const int* in_sizes, int n_in,
                              void* d_out, int out_size, void* d_ws, size_t ws_size,
                              hipStream_t stream) {
    const float* u     = (const float*)d_in[0];
    const float* delta = (const float*)d_in[1];
    const float* A     = (const float*)d_in[2];
    const float* Bm    = (const float*)d_in[3];
    const float* Cm    = (const float*)d_in[4];
    const float* Dv    = (const float*)d_in[5];
    const float* z     = (const float*)d_in[6];
    float* out = (float*)d_out;

    dim3 grid(2 * kD);
    dim3 block(kT);
    hipLaunchKernelGGL(selscan, grid, block, 0, stream,
                       u, delta, A, Bm, Cm, Dv, z, out);
}

// Round 11
// 27.510 us; speedup vs baseline: 1.7379x; 1.1311x over previous
//
#include <hip/hip_runtime.h>
#include <math.h>

namespace {

constexpr int kD = 1024;
constexpr int kL = 1024;
constexpr int kN = 16;
constexpr int kE = 8;    // l-steps per thread
constexpr int kJ = 8;    // n-states per thread
constexpr int kT = 256;  // threads per block; block = one (b,d)

__global__ __launch_bounds__(kT)
void selscan(const float* __restrict__ u,
             const float* __restrict__ delta,
             const float* __restrict__ A,
             const float* __restrict__ Bm,
             const float* __restrict__ Cm,
             const float* __restrict__ Dv,
             const float* __restrict__ z,
             float* __restrict__ out)
{
    // chunk summaries (a,x) per [chunk][n]; +1 float2 pad per row.
    // After the scanner pass, .x of each slot holds the exclusive carry.
    __shared__ float2 sax[128][kN + 1];   // 17408 B
    __shared__ float2 sw[4][kN];          // per-wave 32-chunk totals

    const int bd   = blockIdx.x;
    const int b    = bd >> 10;          // kD = 1024
    const int d    = bd & (kD - 1);
    const int t    = threadIdx.x;
    const int lane = t & 63;
    const int wave = t >> 6;
    const int nh   = t & 1;             // which half of n
    const int n0   = nh << 3;
    const int chunk = t >> 1;           // 0..127
    const int l0   = chunk << 3;        // 8 elements per chunk
    const size_t base = (size_t)bd * kL;

    const float LOG2E = 1.4426950408889634f;
    const float LN2   = 0.6931471805599453f;

    // ---- dt = softplus(delta), dtu = dt*u (exp2/log2 forms) ----
    float dt[kE], dtu[kE];
    {
        float4 d0 = *(const float4*)(delta + base + l0);
        float4 d1 = *(const float4*)(delta + base + l0 + 4);
        float4 u0 = *(const float4*)(u + base + l0);
        float4 u1 = *(const float4*)(u + base + l0 + 4);
        float dd[kE] = {d0.x,d0.y,d0.z,d0.w,d1.x,d1.y,d1.z,d1.w};
        float uu[kE] = {u0.x,u0.y,u0.z,u0.w,u1.x,u1.y,u1.z,u1.w};
        #pragma unroll
        for (int s = 0; s < kE; ++s) {
            float x = dd[s];
            float e = __builtin_amdgcn_exp2f(-fabsf(x) * LOG2E);
            float sp = fmaxf(x, 0.f) + __builtin_amdgcn_logf(1.f + e) * LN2;
            dt[s]  = sp;
            dtu[s] = sp * uu[s];
        }
    }

    // ---- A row, pre-scaled by log2(e) for exp2 ----
    float cj[kJ];
    {
        float4 a0 = *(const float4*)(A + d * kN + n0);
        float4 a1 = *(const float4*)(A + d * kN + n0 + 4);
        cj[0]=a0.x*LOG2E; cj[1]=a0.y*LOG2E; cj[2]=a0.z*LOG2E; cj[3]=a0.w*LOG2E;
        cj[4]=a1.x*LOG2E; cj[5]=a1.y*LOG2E; cj[6]=a1.z*LOG2E; cj[7]=a1.w*LOG2E;
    }

    // ---- Phase 1: local scan; accumulate y_local and Q = P*C ----
    float Q[kJ][kE];
    float y[kE] = {0.f,0.f,0.f,0.f,0.f,0.f,0.f,0.f};
    const int rowbase = (b << 4) + n0;
    #pragma unroll
    for (int j = 0; j < kJ; ++j) {
        const float* Bp = Bm + (size_t)(rowbase + j) * kL + l0;
        const float* Cp = Cm + (size_t)(rowbase + j) * kL + l0;
        float4 b0 = *(const float4*)Bp;
        float4 b1 = *(const float4*)(Bp + 4);
        float4 c0 = *(const float4*)Cp;
        float4 c1 = *(const float4*)(Cp + 4);
        float Bv[kE] = {b0.x,b0.y,b0.z,b0.w,b1.x,b1.y,b1.z,b1.w};
        float Cv[kE] = {c0.x,c0.y,c0.z,c0.w,c1.x,c1.y,c1.z,c1.w};
        float x = 0.f, p = 1.f;
        #pragma unroll
        for (int s = 0; s < kE; ++s) {
            float e = __builtin_amdgcn_exp2f(dt[s] * cj[j]);
            x = fmaf(e, x, dtu[s] * Bv[s]);
            p *= e;
            Q[j][s] = p * Cv[s];
            y[s] = fmaf(x, Cv[s], y[s]);
        }
        sax[chunk][n0 + j] = make_float2(p, x);
    }
    __syncthreads();

    // ---- Scanner: ALL 4 waves; wave w owns chunks [32w, 32w+32) ----
    {
        const int sn = lane & 15;             // state n
        const int q  = lane >> 4;             // sub-group within wave (8 chunks)
        const int cb = (wave << 5) + (q << 3);

        // pass 1: sub-group summary (8 serial steps)
        float p = 1.f, c = 0.f;
        #pragma unroll
        for (int i = 0; i < 8; ++i) {
            float2 ax = sax[cb + i][sn];
            c = fmaf(ax.x, c, ax.y);
            p *= ax.x;
        }
        // in-wave inclusive scan over the 4 sub-groups (strides 16, 32)
        float Aq = p, Xq = c;
        {
            float ain = __shfl_up(Aq, 16, 64);
            float xin = __shfl_up(Xq, 16, 64);
            bool act = (lane >= 16);
            Xq = fmaf(Aq, act ? xin : 0.f, Xq);
            Aq *= act ? ain : 1.f;
            ain = __shfl_up(Aq, 32, 64);
            xin = __shfl_up(Xq, 32, 64);
            act = (lane >= 32);
            Xq = fmaf(Aq, act ? xin : 0.f, Xq);
            Aq *= act ? ain : 1.f;
        }
        // wave-total (q==3 lanes) -> LDS
        if (q == 3) sw[wave][sn] = make_float2(Aq, Xq);
        // in-wave exclusive (shift one sub-group)
        float eA = __shfl_up(Aq, 16, 64);
        float eX = __shfl_up(Xq, 16, 64);
        if (lane < 16) { eA = 1.f; eX = 0.f; }
        __syncthreads();
        // prefix over earlier waves (<=3 serial fma, per sn)
        float wx = 0.f;
        if (wave > 0) {
            wx = sw[0][sn].y;
            if (wave > 1) { float2 s1 = sw[1][sn]; wx = fmaf(s1.x, wx, s1.y); }
            if (wave > 2) { float2 s2 = sw[2][sn]; wx = fmaf(s2.x, wx, s2.y); }
        }
        // carry at this lane's sub-group start
        float cc = fmaf(eA, wx, eX);
        // pass 2: write per-chunk exclusive carry into the .x slot
        #pragma unroll
        for (int i = 0; i < 8; ++i) {
            float2 ax = sax[cb + i][sn];
            sax[cb + i][sn].x = cc;
            cc = fmaf(ax.x, cc, ax.y);
        }
    }
    __syncthreads();

    // ---- Phase 2: y += carry_j * Q_j (carries straight from LDS) ----
    #pragma unroll
    for (int j = 0; j < kJ; ++j) {
        float carry = sax[chunk][n0 + j].x;
        #pragma unroll
        for (int s = 0; s < kE; ++s)
            y[s] = fmaf(carry, Q[j][s], y[s]);
    }

    // ---- Combine the two n-halves (lane pairs) ----
    #pragma unroll
    for (int s = 0; s < kE; ++s) y[s] += __shfl_xor(y[s], 1, 64);

    // ---- Epilogue: each thread of the pair writes 4 of the 8 elements ----
    const float D_d = Dv[d];
    float y0, y1, y2, y3;
    if (nh == 0) { y0 = y[0]; y1 = y[1]; y2 = y[2]; y3 = y[3]; }
    else         { y0 = y[4]; y1 = y[5]; y2 = y[6]; y3 = y[7]; }

    const int eoff = l0 + nh * 4;   // == 4*t, coalesced
    float4 zv = *(const float4*)(z + base + eoff);
    float4 uv = *(const float4*)(u + base + eoff);
    float s0 = __builtin_amdgcn_rcpf(1.f + __builtin_amdgcn_exp2f(-zv.x * LOG2E));
    float s1 = __builtin_amdgcn_rcpf(1.f + __builtin_amdgcn_exp2f(-zv.y * LOG2E));
    float s2 = __builtin_amdgcn_rcpf(1.f + __builtin_amdgcn_exp2f(-zv.z * LOG2E));
    float s3 = __builtin_amdgcn_rcpf(1.f + __builtin_amdgcn_exp2f(-zv.w * LOG2E));
    float4 o;
    o.x = (y0 + uv.x * D_d) * zv.x * s0;
    o.y = (y1 + uv.y * D_d) * zv.y * s1;
    o.z = (y2 + uv.z * D_d) * zv.z * s2;
    o.w = (y3 + uv.w * D_d) * zv.w * s3;
    *(float4*)(out + base + eoff) = o;
}

}  // namespace

extern "C" void kernel_launch(void* const* d_in, const int* in_sizes, int n_in,
                              void* d_out, int out_size, void* d_ws, size_t ws_size,
                              hipStream_t stream) {
    const float* u     = (const float*)d_in[0];
    const float* delta = (const float*)d_in[1];
    const float* A     = (const float*)d_in[2];
    const float* Bm    = (const float*)d_in[3];
    const float* Cm    = (const float*)d_in[4];
    const float* Dv    = (const float*)d_in[5];
    const float* z     = (const float*)d_in[6];
    float* out = (float*)d_out;

    dim3 grid(2 * kD);
    dim3 block(kT);
    hipLaunchKernelGGL(selscan, grid, block, 0, stream,
                       u, delta, A, Bm, Cm, Dv, z, out);
}

// Round 12
// 22.008 us; speedup vs baseline: 2.1723x; 1.2500x over previous
//
#include <hip/hip_runtime.h>
#include <math.h>

namespace {

constexpr int kD = 1024;
constexpr int kL = 1024;
constexpr int kN = 16;
constexpr int kE = 4;     // l-steps per thread
constexpr int kJ = 8;     // n-states per thread (one nh half)
constexpr int kT = 512;   // threads per block; block = one (b,d)
constexpr int kC = 256;   // l-chunks per (b,d)
constexpr int kCP = kC + 1;  // padded chunk stride (transposed layout)

// wave-uniform float -> SGPR
__device__ __forceinline__ float rfl(float x) {
    return __uint_as_float(__builtin_amdgcn_readfirstlane(__float_as_uint(x)));
}

__global__ __launch_bounds__(kT)
void selscan(const float* __restrict__ u,
             const float* __restrict__ delta,
             const float* __restrict__ A,
             const float* __restrict__ Bm,
             const float* __restrict__ Cm,
             const float* __restrict__ Dv,
             const float* __restrict__ z,
             float* __restrict__ out)
{
    __shared__ float2 sax[kN][kCP];  // [n][chunk] (a,x); .x -> carry after scan
    __shared__ float2 sw[8][kN];     // per-wave 32-chunk totals
    __shared__ float2 syr[kC][3];    // upper-half y partials (2 used + pad)

    const int bd   = blockIdx.x;
    const int b    = bd >> 10;          // kD = 1024
    const int d    = bd & (kD - 1);
    const int t    = threadIdx.x;
    const int lane = t & 63;
    const int wave = t >> 6;
    const int nh   = wave >> 2;         // waves 0-3: n 0-7; waves 4-7: n 8-15
    const int n0   = nh << 3;
    const int chunk = ((wave & 3) << 6) | lane;   // 0..255
    const int l0   = chunk << 2;
    const size_t base = (size_t)bd * kL;

    const float LOG2E = 1.4426950408889634f;
    const float LN2   = 0.6931471805599453f;

    // ---- softplus: dt2 = dt*log2e (exponent form), dtu = dt*u ----
    float dt2[kE], dtu[kE];
    {
        float4 dv = *(const float4*)(delta + base + l0);
        float4 uv = *(const float4*)(u + base + l0);
        float dd[4] = {dv.x, dv.y, dv.z, dv.w};
        float uu[4] = {uv.x, uv.y, uv.z, uv.w};
        #pragma unroll
        for (int s = 0; s < kE; ++s) {
            float x = dd[s];
            float e = __builtin_amdgcn_exp2f(-fabsf(x) * LOG2E);
            float sp = fmaxf(x, 0.f) + __builtin_amdgcn_logf(1.f + e) * LN2;
            dt2[s] = sp * LOG2E;
            dtu[s] = sp * uu[s];
        }
    }

    // ---- A row for this wave's n-half -> SGPRs (wave-uniform) ----
    float aj[kJ];
    {
        const float* Ap = A + d * kN + n0;
        #pragma unroll
        for (int j = 0; j < kJ; ++j) aj[j] = rfl(Ap[j]);
    }

    // ---- Phase 1: local 4-step scan; y_local; Q = P*C; summaries ----
    float Q[kJ][kE];
    float y[kE] = {0.f, 0.f, 0.f, 0.f};
    const int rowbase = (b << 4) + n0;
    #pragma unroll
    for (int j = 0; j < kJ; ++j) {
        const float* Bp = Bm + (size_t)(rowbase + j) * kL + l0;
        const float* Cp = Cm + (size_t)(rowbase + j) * kL + l0;
        float4 b4 = *(const float4*)Bp;
        float4 c4 = *(const float4*)Cp;
        float Bv[4] = {b4.x, b4.y, b4.z, b4.w};
        float Cv[4] = {c4.x, c4.y, c4.z, c4.w};
        float x = 0.f, p = 1.f;
        #pragma unroll
        for (int s = 0; s < kE; ++s) {
            float e = __builtin_amdgcn_exp2f(dt2[s] * aj[j]);
            x = fmaf(e, x, dtu[s] * Bv[s]);
            p *= e;
            Q[j][s] = p * Cv[s];
            y[s] = fmaf(x, Cv[s], y[s]);
        }
        sax[n0 + j][chunk] = make_float2(p, x);
    }
    __syncthreads();   // B1

    // ---- Scanner: wave w owns chunks [32w, 32w+32) ----
    {
        const int sn = lane & 15;            // state n
        const int q  = lane >> 4;            // sub-group (8 chunks)
        const int cb = (wave << 5) + (q << 3);

        float p = 1.f, c = 0.f;
        #pragma unroll
        for (int i = 0; i < 8; ++i) {
            float2 ax = sax[sn][cb + i];
            c = fmaf(ax.x, c, ax.y);
            p *= ax.x;
        }
        float Aq = p, Xq = c;
        {   // inclusive scan over the 4 sub-groups (strides 16, 32)
            float ain = __shfl_up(Aq, 16, 64);
            float xin = __shfl_up(Xq, 16, 64);
            bool act = (lane >= 16);
            Xq = fmaf(Aq, act ? xin : 0.f, Xq);
            Aq *= act ? ain : 1.f;
            ain = __shfl_up(Aq, 32, 64);
            xin = __shfl_up(Xq, 32, 64);
            act = (lane >= 32);
            Xq = fmaf(Aq, act ? xin : 0.f, Xq);
            Aq *= act ? ain : 1.f;
        }
        if (q == 3) sw[wave][sn] = make_float2(Aq, Xq);
        float eA = __shfl_up(Aq, 16, 64);
        float eX = __shfl_up(Xq, 16, 64);
        if (lane < 16) { eA = 1.f; eX = 0.f; }
        __syncthreads();   // B2

        float wx = 0.f;    // prefix over earlier waves
        #pragma unroll
        for (int w = 0; w < 7; ++w) {
            if (w < wave) {
                float2 s2 = sw[w][sn];
                wx = fmaf(s2.x, wx, s2.y);
            }
        }
        float cc = fmaf(eA, wx, eX);
        #pragma unroll
        for (int i = 0; i < 8; ++i) {
            float2 ax = sax[sn][cb + i];
            sax[sn][cb + i].x = cc;
            cc = fmaf(ax.x, cc, ax.y);
        }
    }
    __syncthreads();   // B3

    // ---- Phase 2: y += carry_j * Q_j ----
    #pragma unroll
    for (int j = 0; j < kJ; ++j) {
        float carry = sax[n0 + j][chunk].x;
        #pragma unroll
        for (int s = 0; s < kE; ++s)
            y[s] = fmaf(carry, Q[j][s], y[s]);
    }

    // ---- Cross-wave n-half reduce: upper waves publish y ----
    if (nh == 1) {
        syr[chunk][0] = make_float2(y[0], y[1]);
        syr[chunk][1] = make_float2(y[2], y[3]);
    }
    __syncthreads();   // B4

    // ---- Epilogue (lower waves): combine halves, silu, store ----
    if (nh == 0) {
        float2 ya = syr[chunk][0];
        float2 yb = syr[chunk][1];
        float y0 = y[0] + ya.x;
        float y1 = y[1] + ya.y;
        float y2 = y[2] + yb.x;
        float y3 = y[3] + yb.y;

        const float D_d = rfl(Dv[d]);
        float4 uv = *(const float4*)(u + base + l0);
        float4 zv = *(const float4*)(z + base + l0);
        float s0 = __builtin_amdgcn_rcpf(1.f + __builtin_amdgcn_exp2f(-zv.x * LOG2E));
        float s1 = __builtin_amdgcn_rcpf(1.f + __builtin_amdgcn_exp2f(-zv.y * LOG2E));
        float s2 = __builtin_amdgcn_rcpf(1.f + __builtin_amdgcn_exp2f(-zv.z * LOG2E));
        float s3 = __builtin_amdgcn_rcpf(1.f + __builtin_amdgcn_exp2f(-zv.w * LOG2E));
        float4 o;
        o.x = (y0 + uv.x * D_d) * zv.x * s0;
        o.y = (y1 + uv.y * D_d) * zv.y * s1;
        o.z = (y2 + uv.z * D_d) * zv.z * s2;
        o.w = (y3 + uv.w * D_d) * zv.w * s3;
        *(float4*)(out + base + l0) = o;
    }
}

}  // namespace

extern "C" void kernel_launch(void* const* d_in, const int* in_sizes, int n_in,
                              void* d_out, int out_size, void* d_ws, size_t ws_size,
                              hipStream_t stream) {
    const float* u     = (const float*)d_in[0];
    const float* delta = (const float*)d_in[1];
    const float* A     = (const float*)d_in[2];
    const float* Bm    = (const float*)d_in[3];
    const float* Cm    = (const float*)d_in[4];
    const float* Dv    = (const float*)d_in[5];
    const float* z     = (const float*)d_in[6];
    float* out = (float*)d_out;

    dim3 grid(2 * kD);
    dim3 block(kT);
    hipLaunchKernelGGL(selscan, grid, block, 0, stream,
                       u, delta, A, Bm, Cm, Dv, z, out);
}